// Round 10
// baseline (3029.810 us; speedup 1.0000x reference)
//
#include <hip/hip_runtime.h>
#include <hip/hip_fp16.h>

#define ND 56
#define HD 64
#define S1 60   // W1T row stride (words)
#define S2 68   // W2T row stride (words)
#define DEDD_H2 32  // dEdD row = 32 half2 = 64 halfs = 128B (56 used)
#define NREP 16     // force accumulator replicas
#define ESUM_MAX 1024

typedef float v4f __attribute__((ext_vector_type(4)));
typedef _Float16 v4h __attribute__((ext_vector_type(4)));

__global__ __launch_bounds__(256) void zero_kernel(float* __restrict__ p, int n) {
    int i = blockIdx.x * 256 + threadIdx.x;
    if (i < n) p[i] = 0.f;
}

// Persistent MLP fwd+bwd. One wave = 4 atoms (lane = hidden unit).
// REPS>1 instances are timing probes.
template <int REPS>
__global__ __launch_bounds__(256) void mlp_kernel(
    const float* __restrict__ x,        // [natoms*ND]
    const int*   __restrict__ indices,  // [natoms]
    const float* __restrict__ W1,       // [ND*HD]
    const float* __restrict__ b1,       // [HD]
    const float* __restrict__ W2,       // [HD*HD]
    const float* __restrict__ b2,       // [HD]
    const float* __restrict__ W3,       // [HD]
    const float* __restrict__ b3,       // [1]
    float* __restrict__ e_acc,          // [nconf] (ws, pre-zeroed)
    __half2* __restrict__ dEdD,         // [natoms*DEDD_H2]
    int natoms, int nconf)
{
    __shared__ float W1T[HD * S1 + 4];
    __shared__ float W2T[HD * S2];
    __shared__ float b1s[HD], b2s[HD], W3s[HD];
    __shared__ float xs[16 * ND];
    __shared__ float hbuf[4][4][HD];
    __shared__ float gbuf[4][4][HD];
    __shared__ float esum[ESUM_MAX];

    const int tid = threadIdx.x;
    for (int i = tid; i < ND * HD; i += 256) W1T[(i % HD) * S1 + (i / HD)] = W1[i];
    for (int i = tid; i < HD * HD; i += 256) W2T[(i % HD) * S2 + (i / HD)] = W2[i];
    for (int i = tid; i < ESUM_MAX; i += 256) esum[i] = 0.f;
    if (tid < HD) { b1s[tid] = b1[tid]; b2s[tid] = b2[tid]; W3s[tid] = W3[tid]; }
    __syncthreads();

    const int w = tid >> 6, lane = tid & 63;
    const float b3v = b3[0];
    const float b1v = b1s[lane], b2v = b2s[lane], w3v = W3s[lane];
    const int nGroups = (natoms + 15) >> 4;
    const bool ldsE = (nconf <= ESUM_MAX);

    for (int rep = 0; rep < REPS; ++rep) {
    for (int grp = blockIdx.x; grp < nGroups; grp += gridDim.x) {
        const int abase = grp * 16 + w * 4;

        if (lane < 56) {
            const int a = lane / 14;
            if (abase + a < natoms)
                reinterpret_cast<float4*>(xs + w * 4 * ND)[lane] =
                    reinterpret_cast<const float4*>(x)[(size_t)abase * 14 + lane];
        }

        float4 acc[4];
        // ---- fwd layer 1 ----
        #pragma unroll
        for (int a = 0; a < 4; ++a) acc[a] = float4{0.f, 0.f, 0.f, 0.f};
        #pragma unroll
        for (int i = 0; i < 14; ++i) {
            const float4 wv = *reinterpret_cast<const float4*>(&W1T[lane * S1 + 4 * i]);
            #pragma unroll
            for (int a = 0; a < 4; ++a) {
                const float4 xv = *reinterpret_cast<const float4*>(&xs[(w * 4 + a) * ND + 4 * i]);
                acc[a].x = fmaf(wv.x, xv.x, acc[a].x);
                acc[a].y = fmaf(wv.y, xv.y, acc[a].y);
                acc[a].z = fmaf(wv.z, xv.z, acc[a].z);
                acc[a].w = fmaf(wv.w, xv.w, acc[a].w);
            }
        }
        float z1[4], s1[4];
        #pragma unroll
        for (int a = 0; a < 4; ++a) {
            z1[a] = b1v + ((acc[a].x + acc[a].y) + (acc[a].z + acc[a].w));
            s1[a] = 1.f / (1.f + __expf(-z1[a]));
            hbuf[w][a][lane] = z1[a] * s1[a];
        }

        // ---- fwd layer 2 + energy + g2 ----
        #pragma unroll
        for (int a = 0; a < 4; ++a) acc[a] = float4{0.f, 0.f, 0.f, 0.f};
        #pragma unroll
        for (int i = 0; i < 16; ++i) {
            const float4 wv = *reinterpret_cast<const float4*>(&W2T[lane * S2 + 4 * i]);
            #pragma unroll
            for (int a = 0; a < 4; ++a) {
                const float4 hv = *reinterpret_cast<const float4*>(&hbuf[w][a][4 * i]);
                acc[a].x = fmaf(wv.x, hv.x, acc[a].x);
                acc[a].y = fmaf(wv.y, hv.y, acc[a].y);
                acc[a].z = fmaf(wv.z, hv.z, acc[a].z);
                acc[a].w = fmaf(wv.w, hv.w, acc[a].w);
            }
        }
        float ev[4];
        #pragma unroll
        for (int a = 0; a < 4; ++a) {
            const float z2 = b2v + ((acc[a].x + acc[a].y) + (acc[a].z + acc[a].w));
            const float s2 = 1.f / (1.f + __expf(-z2));
            ev[a] = (z2 * s2) * w3v;
            gbuf[w][a][lane] = w3v * (s2 * (1.f + z2 * (1.f - s2)));
        }
        #pragma unroll
        for (int off = 32; off > 0; off >>= 1) {
            #pragma unroll
            for (int a = 0; a < 4; ++a) ev[a] += __shfl_xor(ev[a], off);
        }
        if (lane == 0) {
            #pragma unroll
            for (int a = 0; a < 4; ++a)
                if (abase + a < natoms) {
                    const int conf = indices[abase + a];
                    if (ldsE) atomicAdd(&esum[conf], ev[a] + b3v);
                    else      unsafeAtomicAdd(&e_acc[conf], ev[a] + b3v);
                }
        }

        // ---- bwd: dh1 -> g1 ----
        #pragma unroll
        for (int a = 0; a < 4; ++a) acc[a] = float4{0.f, 0.f, 0.f, 0.f};
        #pragma unroll
        for (int i = 0; i < 16; ++i) {
            const float w0 = W2T[(4 * i + 0) * S2 + lane];
            const float w1v = W2T[(4 * i + 1) * S2 + lane];
            const float w2v = W2T[(4 * i + 2) * S2 + lane];
            const float w3x = W2T[(4 * i + 3) * S2 + lane];
            #pragma unroll
            for (int a = 0; a < 4; ++a) {
                const float4 gv = *reinterpret_cast<const float4*>(&gbuf[w][a][4 * i]);
                acc[a].x = fmaf(w0, gv.x, acc[a].x);
                acc[a].y = fmaf(w1v, gv.y, acc[a].y);
                acc[a].z = fmaf(w2v, gv.z, acc[a].z);
                acc[a].w = fmaf(w3x, gv.w, acc[a].w);
            }
        }
        #pragma unroll
        for (int a = 0; a < 4; ++a) {
            const float dh1 = (acc[a].x + acc[a].y) + (acc[a].z + acc[a].w);
            hbuf[w][a][lane] = dh1 * (s1[a] * (1.f + z1[a] * (1.f - s1[a])));
        }

        // ---- bwd: dx ----
        #pragma unroll
        for (int a = 0; a < 4; ++a) acc[a] = float4{0.f, 0.f, 0.f, 0.f};
        #pragma unroll
        for (int i = 0; i < 16; ++i) {
            const float w0 = W1T[(4 * i + 0) * S1 + lane];
            const float w1v = W1T[(4 * i + 1) * S1 + lane];
            const float w2v = W1T[(4 * i + 2) * S1 + lane];
            const float w3x = W1T[(4 * i + 3) * S1 + lane];
            #pragma unroll
            for (int a = 0; a < 4; ++a) {
                const float4 gv = *reinterpret_cast<const float4*>(&hbuf[w][a][4 * i]);
                acc[a].x = fmaf(w0, gv.x, acc[a].x);
                acc[a].y = fmaf(w1v, gv.y, acc[a].y);
                acc[a].z = fmaf(w2v, gv.z, acc[a].z);
                acc[a].w = fmaf(w3x, gv.w, acc[a].w);
            }
        }
        #pragma unroll
        for (int a = 0; a < 4; ++a) {
            const float v  = (acc[a].x + acc[a].y) + (acc[a].z + acc[a].w);
            const float vh = __shfl_down(v, 1);
            if ((lane & 1) == 0 && lane < ND && abase + a < natoms)
                dEdD[(size_t)(abase + a) * DEDD_H2 + (lane >> 1)] =
                    __floats2half2_rn(v, vh);
        }
    }
    }

    if (ldsE) {
        __syncthreads();
        for (int c = tid; c < nconf; c += 256) {
            const float v = esum[c];
            if (v != 0.f) unsafeAtomicAdd(&e_acc[c], v);
        }
    }
}

// Fused force kernel: 16 lanes per row; replica-keyed scatter.
template <int REPS>
__global__ __launch_bounds__(256) void force_kernel(
    const float* __restrict__ xd,       // [M*ND]
    const int*   __restrict__ xd_indx,  // [M*3]
    const int*   __restrict__ unique_j, // [M]
    const _Float16* __restrict__ dEdD,  // [natoms*64] halfs
    float* __restrict__ f_rep,          // [NREP * 3*natoms] (ws, pre-zeroed)
    int M, int n3)
{
    const long t = (long)blockIdx.x * 256 + threadIdx.x;
    const int  m   = (int)(t >> 4);
    const int  sub = (int)(t & 15);

    for (int rep = 0; rep < REPS; ++rep) {
        float partial = 0.f;
        if (m < M) {
            const int a = __builtin_nontemporal_load(xd_indx + 3 * (size_t)m);
            if (sub < 14) {
                const v4f u = __builtin_nontemporal_load(
                    reinterpret_cast<const v4f*>(xd) + (size_t)m * 14 + sub);
                const v4h hv = reinterpret_cast<const v4h*>(dEdD + ((size_t)a << 6))[sub];
                partial = fmaf(u.x, (float)hv.x,
                          fmaf(u.y, (float)hv.y,
                          fmaf(u.z, (float)hv.z, u.w * (float)hv.w)));
            }
        }
        partial += __shfl_xor(partial, 1);
        partial += __shfl_xor(partial, 2);
        partial += __shfl_xor(partial, 4);
        partial += __shfl_xor(partial, 8);

        if (m < M && sub == 0) {
            const int coord = __builtin_nontemporal_load(xd_indx + 3 * (size_t)m + 2);
            const int j     = __builtin_nontemporal_load(unique_j + m);
            float* dst = f_rep + (size_t)(blockIdx.x & (NREP - 1)) * n3;
            unsafeAtomicAdd(&dst[(size_t)j * 3 + coord], partial);
        }
    }
}

// Merge: out[0:nconf] = e_acc; out[nconf+i] = sum_k f_rep[k][i].
__global__ __launch_bounds__(256) void merge_kernel(
    const float* __restrict__ e_acc, const float* __restrict__ f_rep,
    float* __restrict__ out, int nconf, int n3)
{
    const int i = blockIdx.x * 256 + threadIdx.x;
    if (i < nconf) {
        out[i] = e_acc[i];
    } else if (i < nconf + n3) {
        const int j = i - nconf;
        float s = 0.f;
        #pragma unroll
        for (int k = 0; k < NREP; ++k) s += f_rep[(size_t)k * n3 + j];
        out[i] = s;
    }
}

extern "C" void kernel_launch(void* const* d_in, const int* in_sizes, int n_in,
                              void* d_out, int out_size, void* d_ws, size_t ws_size,
                              hipStream_t stream) {
    const float* x        = (const float*)d_in[0];
    const float* xd       = (const float*)d_in[1];
    const int*   indices  = (const int*)d_in[2];
    const int*   xd_indx  = (const int*)d_in[4];
    const int*   unique_j = (const int*)d_in[5];
    const float* W1 = (const float*)d_in[6];
    const float* b1 = (const float*)d_in[7];
    const float* W2 = (const float*)d_in[8];
    const float* b2 = (const float*)d_in[9];
    const float* W3 = (const float*)d_in[10];
    const float* b3 = (const float*)d_in[11];

    const int natoms = in_sizes[0] / ND;
    const int M      = in_sizes[1] / ND;
    const int nconf  = in_sizes[3];
    const int n3     = 3 * natoms;

    __half2*  dEdD2 = (__half2*)d_ws;                       // 6.4 MB
    _Float16* dEdDh = (_Float16*)d_ws;
    float* e_acc = (float*)((char*)d_ws + (64u << 20));     // [512 pad]
    float* f_rep = e_acc + 512;                             // [NREP*n3] 9.6 MB
    const int accN = 512 + NREP * n3;

    // probe scratch, far from live data
    float*    dum_e  = (float*)((char*)d_ws + (256u << 20));
    float*    dum_f  = dum_e + 512;
    __half2*  dum_d2 = (__half2*)((char*)d_ws + (320u << 20));

    const int nGroups = (natoms + 15) >> 4;
    const int mlpGrid = nGroups < 768 ? nGroups : 768;
    const long fthreads = (long)M * 16;
    const unsigned fGrid = (unsigned)((fthreads + 255) / 256);

    // ---- real sequence ----
    zero_kernel<<<(accN + 255) / 256, 256, 0, stream>>>(e_acc, accN);

    mlp_kernel<1><<<mlpGrid, 256, 0, stream>>>(
        x, indices, W1, b1, W2, b2, W3, b3, e_acc, dEdD2, natoms, nconf);

    force_kernel<1><<<fGrid, 256, 0, stream>>>(
        xd, xd_indx, unique_j, dEdDh, f_rep, M, n3);

    merge_kernel<<<(nconf + n3 + 255) / 256, 256, 0, stream>>>(
        e_acc, f_rep, (float*)d_out, nconf, n3);

    // ---- diagnostic probes (far scratch; rank above harness fills) ----
    mlp_kernel<16><<<mlpGrid, 256, 0, stream>>>(
        x, indices, W1, b1, W2, b2, W3, b3, dum_e, dum_d2, natoms, nconf);

    force_kernel<8><<<fGrid, 256, 0, stream>>>(
        xd, xd_indx, unique_j, dEdDh, dum_f, M, n3);
}

// Round 11
// 430.170 us; speedup vs baseline: 7.0433x; 7.0433x over previous
//
#include <hip/hip_runtime.h>
#include <hip/hip_fp16.h>

#define ND 56
#define HD 64
#define S1 60        // W1T row stride (words)
#define S2 68        // W2T row stride (words)
#define DEDD_H2 32   // dEdD row = 32 half2 = 64 halfs = 128B
#define ESUM_MAX 1024
#define BW 296       // bucket width (floats of output per bucket)
#define NBLK 2048    // blocks for dot/sort chunking
#define NBMAX 1024   // max buckets supported in LDS

typedef float v4f __attribute__((ext_vector_type(4)));
typedef _Float16 v4h __attribute__((ext_vector_type(4)));

__global__ __launch_bounds__(256) void zero_kernel(float* __restrict__ p, int n) {
    int i = blockIdx.x * 256 + threadIdx.x;
    if (i < n) p[i] = 0.f;
}

// Persistent MLP fwd+bwd (round-9 version, unchanged).
__global__ __launch_bounds__(256) void mlp_kernel(
    const float* __restrict__ x, const int* __restrict__ indices,
    const float* __restrict__ W1, const float* __restrict__ b1,
    const float* __restrict__ W2, const float* __restrict__ b2,
    const float* __restrict__ W3, const float* __restrict__ b3,
    float* __restrict__ e_acc, __half2* __restrict__ dEdD,
    int natoms, int nconf)
{
    __shared__ float W1T[HD * S1 + 4];
    __shared__ float W2T[HD * S2];
    __shared__ float b1s[HD], b2s[HD], W3s[HD];
    __shared__ float xs[16 * ND];
    __shared__ float hbuf[4][4][HD];
    __shared__ float gbuf[4][4][HD];
    __shared__ float esum[ESUM_MAX];

    const int tid = threadIdx.x;
    for (int i = tid; i < ND * HD; i += 256) W1T[(i % HD) * S1 + (i / HD)] = W1[i];
    for (int i = tid; i < HD * HD; i += 256) W2T[(i % HD) * S2 + (i / HD)] = W2[i];
    for (int i = tid; i < ESUM_MAX; i += 256) esum[i] = 0.f;
    if (tid < HD) { b1s[tid] = b1[tid]; b2s[tid] = b2[tid]; W3s[tid] = W3[tid]; }
    __syncthreads();

    const int w = tid >> 6, lane = tid & 63;
    const float b3v = b3[0];
    const float b1v = b1s[lane], b2v = b2s[lane], w3v = W3s[lane];
    const int nGroups = (natoms + 15) >> 4;
    const bool ldsE = (nconf <= ESUM_MAX);

    for (int grp = blockIdx.x; grp < nGroups; grp += gridDim.x) {
        const int abase = grp * 16 + w * 4;

        if (lane < 56) {
            const int a = lane / 14;
            if (abase + a < natoms)
                reinterpret_cast<float4*>(xs + w * 4 * ND)[lane] =
                    reinterpret_cast<const float4*>(x)[(size_t)abase * 14 + lane];
        }

        float4 acc[4];
        #pragma unroll
        for (int a = 0; a < 4; ++a) acc[a] = float4{0.f, 0.f, 0.f, 0.f};
        #pragma unroll
        for (int i = 0; i < 14; ++i) {
            const float4 wv = *reinterpret_cast<const float4*>(&W1T[lane * S1 + 4 * i]);
            #pragma unroll
            for (int a = 0; a < 4; ++a) {
                const float4 xv = *reinterpret_cast<const float4*>(&xs[(w * 4 + a) * ND + 4 * i]);
                acc[a].x = fmaf(wv.x, xv.x, acc[a].x);
                acc[a].y = fmaf(wv.y, xv.y, acc[a].y);
                acc[a].z = fmaf(wv.z, xv.z, acc[a].z);
                acc[a].w = fmaf(wv.w, xv.w, acc[a].w);
            }
        }
        float z1[4], s1[4];
        #pragma unroll
        for (int a = 0; a < 4; ++a) {
            z1[a] = b1v + ((acc[a].x + acc[a].y) + (acc[a].z + acc[a].w));
            s1[a] = 1.f / (1.f + __expf(-z1[a]));
            hbuf[w][a][lane] = z1[a] * s1[a];
        }

        #pragma unroll
        for (int a = 0; a < 4; ++a) acc[a] = float4{0.f, 0.f, 0.f, 0.f};
        #pragma unroll
        for (int i = 0; i < 16; ++i) {
            const float4 wv = *reinterpret_cast<const float4*>(&W2T[lane * S2 + 4 * i]);
            #pragma unroll
            for (int a = 0; a < 4; ++a) {
                const float4 hv = *reinterpret_cast<const float4*>(&hbuf[w][a][4 * i]);
                acc[a].x = fmaf(wv.x, hv.x, acc[a].x);
                acc[a].y = fmaf(wv.y, hv.y, acc[a].y);
                acc[a].z = fmaf(wv.z, hv.z, acc[a].z);
                acc[a].w = fmaf(wv.w, hv.w, acc[a].w);
            }
        }
        float ev[4];
        #pragma unroll
        for (int a = 0; a < 4; ++a) {
            const float z2 = b2v + ((acc[a].x + acc[a].y) + (acc[a].z + acc[a].w));
            const float s2 = 1.f / (1.f + __expf(-z2));
            ev[a] = (z2 * s2) * w3v;
            gbuf[w][a][lane] = w3v * (s2 * (1.f + z2 * (1.f - s2)));
        }
        #pragma unroll
        for (int off = 32; off > 0; off >>= 1) {
            #pragma unroll
            for (int a = 0; a < 4; ++a) ev[a] += __shfl_xor(ev[a], off);
        }
        if (lane == 0) {
            #pragma unroll
            for (int a = 0; a < 4; ++a)
                if (abase + a < natoms) {
                    const int conf = indices[abase + a];
                    if (ldsE) atomicAdd(&esum[conf], ev[a] + b3v);
                    else      unsafeAtomicAdd(&e_acc[conf], ev[a] + b3v);
                }
        }

        #pragma unroll
        for (int a = 0; a < 4; ++a) acc[a] = float4{0.f, 0.f, 0.f, 0.f};
        #pragma unroll
        for (int i = 0; i < 16; ++i) {
            const float w0 = W2T[(4 * i + 0) * S2 + lane];
            const float w1v = W2T[(4 * i + 1) * S2 + lane];
            const float w2v = W2T[(4 * i + 2) * S2 + lane];
            const float w3x = W2T[(4 * i + 3) * S2 + lane];
            #pragma unroll
            for (int a = 0; a < 4; ++a) {
                const float4 gv = *reinterpret_cast<const float4*>(&gbuf[w][a][4 * i]);
                acc[a].x = fmaf(w0, gv.x, acc[a].x);
                acc[a].y = fmaf(w1v, gv.y, acc[a].y);
                acc[a].z = fmaf(w2v, gv.z, acc[a].z);
                acc[a].w = fmaf(w3x, gv.w, acc[a].w);
            }
        }
        #pragma unroll
        for (int a = 0; a < 4; ++a) {
            const float dh1 = (acc[a].x + acc[a].y) + (acc[a].z + acc[a].w);
            hbuf[w][a][lane] = dh1 * (s1[a] * (1.f + z1[a] * (1.f - s1[a])));
        }

        #pragma unroll
        for (int a = 0; a < 4; ++a) acc[a] = float4{0.f, 0.f, 0.f, 0.f};
        #pragma unroll
        for (int i = 0; i < 16; ++i) {
            const float w0 = W1T[(4 * i + 0) * S1 + lane];
            const float w1v = W1T[(4 * i + 1) * S1 + lane];
            const float w2v = W1T[(4 * i + 2) * S1 + lane];
            const float w3x = W1T[(4 * i + 3) * S1 + lane];
            #pragma unroll
            for (int a = 0; a < 4; ++a) {
                const float4 gv = *reinterpret_cast<const float4*>(&hbuf[w][a][4 * i]);
                acc[a].x = fmaf(w0, gv.x, acc[a].x);
                acc[a].y = fmaf(w1v, gv.y, acc[a].y);
                acc[a].z = fmaf(w2v, gv.z, acc[a].z);
                acc[a].w = fmaf(w3x, gv.w, acc[a].w);
            }
        }
        #pragma unroll
        for (int a = 0; a < 4; ++a) {
            const float v  = (acc[a].x + acc[a].y) + (acc[a].z + acc[a].w);
            const float vh = __shfl_down(v, 1);
            if ((lane & 1) == 0 && lane < ND && abase + a < natoms)
                dEdD[(size_t)(abase + a) * DEDD_H2 + (lane >> 1)] =
                    __floats2half2_rn(v, vh);
        }
    }

    if (ldsE) {
        __syncthreads();
        for (int c = tid; c < nconf; c += 256) {
            const float v = esum[c];
            if (v != 0.f) unsafeAtomicAdd(&e_acc[c], v);
        }
    }
}

// A: dot + pair emit + per-block bucket histogram. NO global atomics.
__global__ __launch_bounds__(256) void force_dot(
    const float* __restrict__ xd, const int* __restrict__ xd_indx,
    const int* __restrict__ unique_j, const _Float16* __restrict__ dEdD,
    int2* __restrict__ pairs, int* __restrict__ hist,
    int M, int NB, int CH)
{
    __shared__ int lh[NBMAX];
    const int b = blockIdx.x, tid = threadIdx.x;
    for (int i = tid; i < NB; i += 256) lh[i] = 0;
    __syncthreads();

    const int mstart = b * CH;
    const int mend   = min(mstart + CH, M);
    const int sub = tid & 15, team = tid >> 4;

    for (int m0 = mstart; m0 < mend; m0 += 16) {
        const int m = m0 + team;
        float partial = 0.f;
        if (m < mend) {
            const int a = __builtin_nontemporal_load(xd_indx + 3 * (size_t)m);
            if (sub < 14) {
                const v4f u = __builtin_nontemporal_load(
                    reinterpret_cast<const v4f*>(xd) + (size_t)m * 14 + sub);
                const v4h hv = reinterpret_cast<const v4h*>(dEdD + ((size_t)a << 6))[sub];
                partial = fmaf(u.x, (float)hv.x,
                          fmaf(u.y, (float)hv.y,
                          fmaf(u.z, (float)hv.z, u.w * (float)hv.w)));
            }
        }
        partial += __shfl_xor(partial, 1);
        partial += __shfl_xor(partial, 2);
        partial += __shfl_xor(partial, 4);
        partial += __shfl_xor(partial, 8);

        if (m < mend && sub == 0) {
            const int coord = __builtin_nontemporal_load(xd_indx + 3 * (size_t)m + 2);
            const int j     = __builtin_nontemporal_load(unique_j + m);
            const int seg   = j * 3 + coord;
            int2 pr; pr.x = seg; pr.y = __float_as_int(partial);
            __builtin_nontemporal_store(pr.x, &pairs[m].x);
            __builtin_nontemporal_store(pr.y, &pairs[m].y);
            atomicAdd(&lh[(unsigned)seg / BW], 1);
        }
    }
    __syncthreads();
    for (int i = tid; i < NB; i += 256) hist[(size_t)b * NB + i] = lh[i];
}

// P1: per-bucket exclusive prefix over NBLK block-counts (in place) + totals.
__global__ __launch_bounds__(256) void prefix1(
    int* __restrict__ hist, int* __restrict__ totals, int NB)
{
    const int k = blockIdx.x, t = threadIdx.x;
    __shared__ int s[256];
    int v[NBLK / 256];
    int sum = 0;
    #pragma unroll
    for (int j = 0; j < NBLK / 256; ++j) {
        v[j] = hist[(size_t)(t * (NBLK / 256) + j) * NB + k];
        sum += v[j];
    }
    s[t] = sum;
    __syncthreads();
    for (int d = 1; d < 256; d <<= 1) {
        const int add = (t >= d) ? s[t - d] : 0;
        __syncthreads();
        s[t] += add;
        __syncthreads();
    }
    if (t == 255) totals[k] = s[255];
    int run = (t == 0) ? 0 : s[t - 1];
    #pragma unroll
    for (int j = 0; j < NBLK / 256; ++j) {
        const int tv = v[j];
        hist[(size_t)(t * (NBLK / 256) + j) * NB + k] = run;
        run += tv;
    }
}

// P2: exclusive scan of bucket totals -> bucket base offsets.
__global__ __launch_bounds__(512) void prefix2(
    const int* __restrict__ totals, int* __restrict__ base, int NB)
{
    __shared__ int s[512];
    const int t = threadIdx.x;
    const int v = (t < NB) ? totals[t] : 0;
    s[t] = v;
    __syncthreads();
    for (int d = 1; d < 512; d <<= 1) {
        const int add = (t >= d) ? s[t - d] : 0;
        __syncthreads();
        s[t] += add;
        __syncthreads();
    }
    if (t < NB) base[t] = s[t] - v;
}

// B: scatter pairs into bucket-sorted order via LDS cursors. No global atomics.
__global__ __launch_bounds__(256) void force_sort(
    const int2* __restrict__ pairs, const int* __restrict__ hist,
    const int* __restrict__ base, int2* __restrict__ sorted,
    int M, int NB, int CH)
{
    __shared__ int cnt[NBMAX];
    const int b = blockIdx.x, tid = threadIdx.x;
    for (int k = tid; k < NB; k += 256)
        cnt[k] = hist[(size_t)b * NB + k] + base[k];
    __syncthreads();

    const int mstart = b * CH;
    const int mend   = min(mstart + CH, M);
    for (int m = mstart + tid; m < mend; m += 256) {
        const int2 pr = pairs[m];
        const int k = (unsigned)pr.x / BW;
        const int r = atomicAdd(&cnt[k], 1);
        sorted[r] = pr;
    }
}

// C: per-bucket LDS reduce, plain coalesced stores to output. No global atomics.
__global__ __launch_bounds__(256) void force_reduce(
    const int2* __restrict__ sorted, const int* __restrict__ base,
    const int* __restrict__ totals, float* __restrict__ out,
    int n3, int nconf)
{
    const int k = blockIdx.x, tid = threadIdx.x;
    __shared__ float acc[BW];
    for (int i = tid; i < BW; i += 256) acc[i] = 0.f;
    __syncthreads();
    const int s0 = base[k], s1 = s0 + totals[k];
    for (int i = s0 + tid; i < s1; i += 256) {
        const int2 pr = sorted[i];
        atomicAdd(&acc[pr.x - k * BW], __int_as_float(pr.y));
    }
    __syncthreads();
    const int g0 = k * BW;
    for (int i = tid; i < BW; i += 256)
        if (g0 + i < n3) out[nconf + g0 + i] = acc[i];
}

__global__ __launch_bounds__(256) void energy_copy(
    const float* __restrict__ e_acc, float* __restrict__ out, int nconf)
{
    const int i = blockIdx.x * 256 + threadIdx.x;
    if (i < nconf) out[i] = e_acc[i];
}

extern "C" void kernel_launch(void* const* d_in, const int* in_sizes, int n_in,
                              void* d_out, int out_size, void* d_ws, size_t ws_size,
                              hipStream_t stream) {
    const float* x        = (const float*)d_in[0];
    const float* xd       = (const float*)d_in[1];
    const int*   indices  = (const int*)d_in[2];
    const int*   xd_indx  = (const int*)d_in[4];
    const int*   unique_j = (const int*)d_in[5];
    const float* W1 = (const float*)d_in[6];
    const float* b1 = (const float*)d_in[7];
    const float* W2 = (const float*)d_in[8];
    const float* b2 = (const float*)d_in[9];
    const float* W3 = (const float*)d_in[10];
    const float* b3 = (const float*)d_in[11];

    const int natoms = in_sizes[0] / ND;
    const int M      = in_sizes[1] / ND;
    const int nconf  = in_sizes[3];
    const int n3     = 3 * natoms;
    const int NB     = (n3 + BW - 1) / BW;        // 507 (<= NBMAX)
    const int CH     = (M + NBLK - 1) / NBLK;     // rows per chunk block

    __half2*  dEdD2 = (__half2*)d_ws;                         // 6.4 MB
    _Float16* dEdDh = (_Float16*)d_ws;
    float* e_acc  = (float*)((char*)d_ws + (64u  << 20));     // [512]
    int2*  pairs  = (int2*) ((char*)d_ws + (128u << 20));     // 24 MB
    int2*  sorted = (int2*) ((char*)d_ws + (192u << 20));     // 24 MB
    int*   hist   = (int*)  ((char*)d_ws + (256u << 20));     // NBLK*NB (~4.2 MB)
    int*   totals = (int*)  ((char*)d_ws + (288u << 20));     // [NB]
    int*   basep  = totals + 2048;                            // [NB]

    zero_kernel<<<2, 256, 0, stream>>>(e_acc, 512);

    const int nGroups = (natoms + 15) >> 4;
    const int mlpGrid = nGroups < 768 ? nGroups : 768;
    mlp_kernel<<<mlpGrid, 256, 0, stream>>>(
        x, indices, W1, b1, W2, b2, W3, b3, e_acc, dEdD2, natoms, nconf);

    force_dot<<<NBLK, 256, 0, stream>>>(
        xd, xd_indx, unique_j, dEdDh, pairs, hist, M, NB, CH);

    prefix1<<<NB, 256, 0, stream>>>(hist, totals, NB);
    prefix2<<<1, 512, 0, stream>>>(totals, basep, NB);

    force_sort<<<NBLK, 256, 0, stream>>>(pairs, hist, basep, sorted, M, NB, CH);

    force_reduce<<<NB, 256, 0, stream>>>(sorted, basep, totals, (float*)d_out, n3, nconf);

    energy_copy<<<(nconf + 255) / 256, 256, 0, stream>>>(e_acc, (float*)d_out, nconf);
}

// Round 12
// 325.129 us; speedup vs baseline: 9.3188x; 1.3231x over previous
//
#include <hip/hip_runtime.h>
#include <hip/hip_fp16.h>

#define ND 56
#define HD 64
#define S1 60        // W1T row stride (words)
#define S2 68        // W2T row stride (words)
#define DEDD_H2 32   // dEdD row = 32 half2 = 64 halfs = 128B
#define ESUM_MAX 1024
#define FBLK 2048    // force grid blocks

typedef float v4f __attribute__((ext_vector_type(4)));
typedef _Float16 v4h __attribute__((ext_vector_type(4)));

__global__ __launch_bounds__(256) void zero_kernel(float* __restrict__ p, int n) {
    int i = blockIdx.x * 256 + threadIdx.x;
    if (i < n) p[i] = 0.f;
}

// Persistent MLP fwd+bwd (round-9 version, unchanged; writes energy via LDS
// per-config accumulation, one global atomic per touched config per block).
__global__ __launch_bounds__(256) void mlp_kernel(
    const float* __restrict__ x, const int* __restrict__ indices,
    const float* __restrict__ W1, const float* __restrict__ b1,
    const float* __restrict__ W2, const float* __restrict__ b2,
    const float* __restrict__ W3, const float* __restrict__ b3,
    float* __restrict__ e_out, __half2* __restrict__ dEdD,
    int natoms, int nconf)
{
    __shared__ float W1T[HD * S1 + 4];
    __shared__ float W2T[HD * S2];
    __shared__ float b1s[HD], b2s[HD], W3s[HD];
    __shared__ float xs[16 * ND];
    __shared__ float hbuf[4][4][HD];
    __shared__ float gbuf[4][4][HD];
    __shared__ float esum[ESUM_MAX];

    const int tid = threadIdx.x;
    for (int i = tid; i < ND * HD; i += 256) W1T[(i % HD) * S1 + (i / HD)] = W1[i];
    for (int i = tid; i < HD * HD; i += 256) W2T[(i % HD) * S2 + (i / HD)] = W2[i];
    for (int i = tid; i < ESUM_MAX; i += 256) esum[i] = 0.f;
    if (tid < HD) { b1s[tid] = b1[tid]; b2s[tid] = b2[tid]; W3s[tid] = W3[tid]; }
    __syncthreads();

    const int w = tid >> 6, lane = tid & 63;
    const float b3v = b3[0];
    const float b1v = b1s[lane], b2v = b2s[lane], w3v = W3s[lane];
    const int nGroups = (natoms + 15) >> 4;
    const bool ldsE = (nconf <= ESUM_MAX);

    for (int grp = blockIdx.x; grp < nGroups; grp += gridDim.x) {
        const int abase = grp * 16 + w * 4;

        if (lane < 56) {
            const int a = lane / 14;
            if (abase + a < natoms)
                reinterpret_cast<float4*>(xs + w * 4 * ND)[lane] =
                    reinterpret_cast<const float4*>(x)[(size_t)abase * 14 + lane];
        }

        float4 acc[4];
        #pragma unroll
        for (int a = 0; a < 4; ++a) acc[a] = float4{0.f, 0.f, 0.f, 0.f};
        #pragma unroll
        for (int i = 0; i < 14; ++i) {
            const float4 wv = *reinterpret_cast<const float4*>(&W1T[lane * S1 + 4 * i]);
            #pragma unroll
            for (int a = 0; a < 4; ++a) {
                const float4 xv = *reinterpret_cast<const float4*>(&xs[(w * 4 + a) * ND + 4 * i]);
                acc[a].x = fmaf(wv.x, xv.x, acc[a].x);
                acc[a].y = fmaf(wv.y, xv.y, acc[a].y);
                acc[a].z = fmaf(wv.z, xv.z, acc[a].z);
                acc[a].w = fmaf(wv.w, xv.w, acc[a].w);
            }
        }
        float z1[4], s1[4];
        #pragma unroll
        for (int a = 0; a < 4; ++a) {
            z1[a] = b1v + ((acc[a].x + acc[a].y) + (acc[a].z + acc[a].w));
            s1[a] = 1.f / (1.f + __expf(-z1[a]));
            hbuf[w][a][lane] = z1[a] * s1[a];
        }

        #pragma unroll
        for (int a = 0; a < 4; ++a) acc[a] = float4{0.f, 0.f, 0.f, 0.f};
        #pragma unroll
        for (int i = 0; i < 16; ++i) {
            const float4 wv = *reinterpret_cast<const float4*>(&W2T[lane * S2 + 4 * i]);
            #pragma unroll
            for (int a = 0; a < 4; ++a) {
                const float4 hv = *reinterpret_cast<const float4*>(&hbuf[w][a][4 * i]);
                acc[a].x = fmaf(wv.x, hv.x, acc[a].x);
                acc[a].y = fmaf(wv.y, hv.y, acc[a].y);
                acc[a].z = fmaf(wv.z, hv.z, acc[a].z);
                acc[a].w = fmaf(wv.w, hv.w, acc[a].w);
            }
        }
        float ev[4];
        #pragma unroll
        for (int a = 0; a < 4; ++a) {
            const float z2 = b2v + ((acc[a].x + acc[a].y) + (acc[a].z + acc[a].w));
            const float s2 = 1.f / (1.f + __expf(-z2));
            ev[a] = (z2 * s2) * w3v;
            gbuf[w][a][lane] = w3v * (s2 * (1.f + z2 * (1.f - s2)));
        }
        #pragma unroll
        for (int off = 32; off > 0; off >>= 1) {
            #pragma unroll
            for (int a = 0; a < 4; ++a) ev[a] += __shfl_xor(ev[a], off);
        }
        if (lane == 0) {
            #pragma unroll
            for (int a = 0; a < 4; ++a)
                if (abase + a < natoms) {
                    const int conf = indices[abase + a];
                    if (ldsE) atomicAdd(&esum[conf], ev[a] + b3v);
                    else      unsafeAtomicAdd(&e_out[conf], ev[a] + b3v);
                }
        }

        #pragma unroll
        for (int a = 0; a < 4; ++a) acc[a] = float4{0.f, 0.f, 0.f, 0.f};
        #pragma unroll
        for (int i = 0; i < 16; ++i) {
            const float w0 = W2T[(4 * i + 0) * S2 + lane];
            const float w1v = W2T[(4 * i + 1) * S2 + lane];
            const float w2v = W2T[(4 * i + 2) * S2 + lane];
            const float w3x = W2T[(4 * i + 3) * S2 + lane];
            #pragma unroll
            for (int a = 0; a < 4; ++a) {
                const float4 gv = *reinterpret_cast<const float4*>(&gbuf[w][a][4 * i]);
                acc[a].x = fmaf(w0, gv.x, acc[a].x);
                acc[a].y = fmaf(w1v, gv.y, acc[a].y);
                acc[a].z = fmaf(w2v, gv.z, acc[a].z);
                acc[a].w = fmaf(w3x, gv.w, acc[a].w);
            }
        }
        #pragma unroll
        for (int a = 0; a < 4; ++a) {
            const float dh1 = (acc[a].x + acc[a].y) + (acc[a].z + acc[a].w);
            hbuf[w][a][lane] = dh1 * (s1[a] * (1.f + z1[a] * (1.f - s1[a])));
        }

        #pragma unroll
        for (int a = 0; a < 4; ++a) acc[a] = float4{0.f, 0.f, 0.f, 0.f};
        #pragma unroll
        for (int i = 0; i < 16; ++i) {
            const float w0 = W1T[(4 * i + 0) * S1 + lane];
            const float w1v = W1T[(4 * i + 1) * S1 + lane];
            const float w2v = W1T[(4 * i + 2) * S1 + lane];
            const float w3x = W1T[(4 * i + 3) * S1 + lane];
            #pragma unroll
            for (int a = 0; a < 4; ++a) {
                const float4 gv = *reinterpret_cast<const float4*>(&hbuf[w][a][4 * i]);
                acc[a].x = fmaf(w0, gv.x, acc[a].x);
                acc[a].y = fmaf(w1v, gv.y, acc[a].y);
                acc[a].z = fmaf(w2v, gv.z, acc[a].z);
                acc[a].w = fmaf(w3x, gv.w, acc[a].w);
            }
        }
        #pragma unroll
        for (int a = 0; a < 4; ++a) {
            const float v  = (acc[a].x + acc[a].y) + (acc[a].z + acc[a].w);
            const float vh = __shfl_down(v, 1);
            if ((lane & 1) == 0 && lane < ND && abase + a < natoms)
                dEdD[(size_t)(abase + a) * DEDD_H2 + (lane >> 1)] =
                    __floats2half2_rn(v, vh);
        }
    }

    if (ldsE) {
        __syncthreads();
        for (int c = tid; c < nconf; c += 256) {
            const float v = esum[c];
            if (v != 0.f) unsafeAtomicAdd(&e_out[c], v);
        }
    }
}

// Grid-strided force kernel: 16-lane team per row, ~92 rows per team.
// Atomic issued fire-and-forget mid-loop -> scatter drain overlaps the
// xd stream instead of following it. Direct scatter into d_out.
__global__ __launch_bounds__(256) void force_kernel(
    const float* __restrict__ xd,       // [M*ND]
    const int*   __restrict__ xd_indx,  // [M*3]
    const int*   __restrict__ unique_j, // [M]
    const _Float16* __restrict__ dEdD,  // [natoms*64] halfs
    float* __restrict__ out_f,          // [3*natoms] (pre-zeroed d_out region)
    int M, int CH)
{
    const int b = blockIdx.x, tid = threadIdx.x;
    const int team = tid >> 4, sub = tid & 15;   // 16 teams/block
    const int mstart = b * CH;
    const int mend   = min(mstart + CH, M);

    for (int m0 = mstart; m0 < mend; m0 += 16) {
        const int m = m0 + team;   // wave covers 4 consecutive rows (896B span)
        float partial = 0.f;
        const bool act = (m < mend);
        if (act && sub < 14) {
            const int a = __builtin_nontemporal_load(xd_indx + 3 * (size_t)m);
            const v4f u = __builtin_nontemporal_load(
                reinterpret_cast<const v4f*>(xd) + (size_t)m * 14 + sub);
            const v4h hv = reinterpret_cast<const v4h*>(dEdD + ((size_t)a << 6))[sub];
            partial = fmaf(u.x, (float)hv.x,
                      fmaf(u.y, (float)hv.y,
                      fmaf(u.z, (float)hv.z, u.w * (float)hv.w)));
        }
        partial += __shfl_xor(partial, 1);
        partial += __shfl_xor(partial, 2);
        partial += __shfl_xor(partial, 4);
        partial += __shfl_xor(partial, 8);

        if (act && sub == 0) {
            const int coord = __builtin_nontemporal_load(xd_indx + 3 * (size_t)m + 2);
            const int j     = __builtin_nontemporal_load(unique_j + m);
            unsafeAtomicAdd(&out_f[(size_t)j * 3 + coord], partial);
        }
    }
}

extern "C" void kernel_launch(void* const* d_in, const int* in_sizes, int n_in,
                              void* d_out, int out_size, void* d_ws, size_t ws_size,
                              hipStream_t stream) {
    const float* x        = (const float*)d_in[0];
    const float* xd       = (const float*)d_in[1];
    const int*   indices  = (const int*)d_in[2];
    const int*   xd_indx  = (const int*)d_in[4];
    const int*   unique_j = (const int*)d_in[5];
    const float* W1 = (const float*)d_in[6];
    const float* b1 = (const float*)d_in[7];
    const float* W2 = (const float*)d_in[8];
    const float* b2 = (const float*)d_in[9];
    const float* W3 = (const float*)d_in[10];
    const float* b3 = (const float*)d_in[11];

    const int natoms = in_sizes[0] / ND;
    const int M      = in_sizes[1] / ND;
    const int nconf  = in_sizes[3];

    float*    out_e = (float*)d_out;           // [nconf]
    float*    out_f = out_e + nconf;           // [3*natoms]
    __half2*  dEdD2 = (__half2*)d_ws;          // [natoms*32] half2 (6.4 MB)
    _Float16* dEdDh = (_Float16*)d_ws;

    // d_out is poisoned once before timing; zero it every call.
    zero_kernel<<<(out_size + 255) / 256, 256, 0, stream>>>((float*)d_out, out_size);

    const int nGroups = (natoms + 15) >> 4;
    const int mlpGrid = nGroups < 768 ? nGroups : 768;
    mlp_kernel<<<mlpGrid, 256, 0, stream>>>(
        x, indices, W1, b1, W2, b2, W3, b3, out_e, dEdD2, natoms, nconf);

    const int CH = (M + FBLK - 1) / FBLK;
    force_kernel<<<FBLK, 256, 0, stream>>>(
        xd, xd_indx, unique_j, dEdDh, out_f, M, CH);
}